// Round 1
// baseline (186.598 us; speedup 1.0000x reference)
//
#include <hip/hip_runtime.h>

typedef unsigned short u16;
typedef unsigned int u32;
typedef __bf16 bf16x8 __attribute__((ext_vector_type(8)));
typedef float f32x4 __attribute__((ext_vector_type(4)));

#define LOG2E 1.44269504088896340736f

__device__ __forceinline__ u16 f2bf(float f) {
  u32 u = __builtin_bit_cast(u32, f);
  u32 r = (u + 0x7FFFu + ((u >> 16) & 1u)) >> 16;  // RNE, no NaN inputs here
  return (u16)r;
}

// ---------------------------------------------------------------------------
// Projection: Qb = relu(x Wq + bq) * 0.125 (scale folded), Kb = relu(x Wk + bk),
// VbT = relu(x Wv + bv) stored TRANSPOSED as [B][128][N] so the attention
// kernel can ds_read_b128 the PV B-operand.
// grid = B*N/16 = 2048 blocks, 128 threads (thread = output column d).
// ---------------------------------------------------------------------------
__global__ __launch_bounds__(128) void proj_kernel(
    const float* __restrict__ x,
    const float* __restrict__ Wq, const float* __restrict__ bq,
    const float* __restrict__ Wk, const float* __restrict__ bk,
    const float* __restrict__ Wv, const float* __restrict__ bv,
    u16* __restrict__ Qb, u16* __restrict__ Kb, u16* __restrict__ VbT) {
  __shared__ float xs[16 * 64];
  const int t = threadIdx.x;                     // 0..127 == d
  const size_t rg0 = (size_t)blockIdx.x * 16;    // global row base (b*2048+n)

  const float4* xsrc = reinterpret_cast<const float4*>(x + rg0 * 64);
  float4* xdst = reinterpret_cast<float4*>(xs);
#pragma unroll
  for (int i = 0; i < 2; ++i) xdst[t + i * 128] = xsrc[t + i * 128];
  __syncthreads();

  float aq[16], ak[16], av[16];
#pragma unroll
  for (int r = 0; r < 16; ++r) { aq[r] = 0.f; ak[r] = 0.f; av[r] = 0.f; }
  for (int c = 0; c < 64; ++c) {
    float wq = Wq[c * 128 + t], wk = Wk[c * 128 + t], wv = Wv[c * 128 + t];
#pragma unroll
    for (int r = 0; r < 16; ++r) {
      float xv = xs[r * 64 + c];   // wave-uniform address -> LDS broadcast
      aq[r] = fmaf(xv, wq, aq[r]);
      ak[r] = fmaf(xv, wk, ak[r]);
      av[r] = fmaf(xv, wv, av[r]);
    }
  }
  const float biasq = bq[t], biask = bk[t], biasv = bv[t];
#pragma unroll
  for (int r = 0; r < 16; ++r) {
    Qb[(rg0 + r) * 128 + t] = f2bf(fmaxf(aq[r] + biasq, 0.f) * 0.125f);
    Kb[(rg0 + r) * 128 + t] = f2bf(fmaxf(ak[r] + biask, 0.f));
  }
  // V transposed store: 16 contiguous bf16 along n per thread -> 2x dwordx4
  const int b = (int)(rg0 >> 11);
  const int n0 = (int)(rg0 & 2047);
  u32 pk[8];
#pragma unroll
  for (int i = 0; i < 8; ++i) {
    u16 lo = f2bf(fmaxf(av[2 * i] + biasv, 0.f));
    u16 hi = f2bf(fmaxf(av[2 * i + 1] + biasv, 0.f));
    pk[i] = (u32)lo | ((u32)hi << 16);
  }
  uint4* vdst = reinterpret_cast<uint4*>(VbT + ((size_t)(b * 128 + t)) * 2048 + n0);
  vdst[0] = make_uint4(pk[0], pk[1], pk[2], pk[3]);
  vdst[1] = make_uint4(pk[4], pk[5], pk[6], pk[7]);
}

// ---------------------------------------------------------------------------
// Flash attention. grid = 16 batches * 32 q-tiles = 512 blocks, 256 threads
// (4 waves). Wave w owns q-rows [qt*64 + w*16, +16). KV tiles of 64 staged in
// LDS (XOR-swizzled). 16x16x32 bf16 MFMA.
// Fragment layouts (gfx950): A/B frag = 8 contiguous k at row lane&15,
// k-base (lane>>4)*8. C/D: col=lane&15, row=(lane>>4)*4+reg (m89-verified).
// ---------------------------------------------------------------------------
__global__ __launch_bounds__(256) void attn_kernel(
    const u16* __restrict__ Qb, const u16* __restrict__ Kb,
    const u16* __restrict__ VbT, float* __restrict__ out) {
  __shared__ __align__(16) u16 Ks[64 * 128];      // [kv][d], swizzled
  __shared__ __align__(16) u16 Vs[128 * 64];      // V^T [d][kv], swizzled
  __shared__ __align__(16) u16 Ps[4][16 * 72];    // per-wave P, row stride 72

  const int b = blockIdx.x >> 5;
  const int qt = blockIdx.x & 31;
  const int t = threadIdx.x, w = t >> 6, lane = t & 63;
  const int g = lane >> 4, lr = lane & 15;
  const int q0 = qt * 64 + w * 16;

  // Q fragments hoisted (scale already folded in)
  bf16x8 qf[4];
  const u16* Qrow = Qb + ((size_t)(b * 2048 + q0 + lr)) * 128;
#pragma unroll
  for (int dc = 0; dc < 4; ++dc)
    qf[dc] = *reinterpret_cast<const bf16x8*>(Qrow + dc * 32 + g * 8);

  f32x4 Oacc[8];
#pragma unroll
  for (int dt = 0; dt < 8; ++dt)
#pragma unroll
    for (int r = 0; r < 4; ++r) Oacc[dt][r] = 0.f;
  float mrow[4], lrow[4];
#pragma unroll
  for (int r = 0; r < 4; ++r) { mrow[r] = -INFINITY; lrow[r] = 0.f; }

  const u16* Kbase = Kb + (size_t)b * 2048 * 128;
  const u16* Vbase = VbT + (size_t)b * 128 * 2048;
  char* KsB = reinterpret_cast<char*>(Ks);
  char* VsB = reinterpret_cast<char*>(Vs);

  for (int kt = 0; kt < 32; ++kt) {
    const int kv0 = kt * 64;
    __syncthreads();   // previous tile's LDS reads done
    // stage K tile [64][128]: 1024 16B chunks, 4 per thread, coalesced
#pragma unroll
    for (int i = 0; i < 4; ++i) {
      int id = t + i * 256;
      int row = id >> 4, c = id & 15;
      uint4 v = *reinterpret_cast<const uint4*>(Kbase + (size_t)(kv0 + row) * 128 + c * 8);
      *reinterpret_cast<uint4*>(KsB + row * 256 + ((c * 16) ^ ((row & 7) << 4))) = v;
    }
    // stage V^T tile [128][64]
#pragma unroll
    for (int i = 0; i < 4; ++i) {
      int id = t + i * 256;
      int dr = id >> 3, c = id & 7;
      uint4 v = *reinterpret_cast<const uint4*>(Vbase + (size_t)dr * 2048 + kv0 + c * 8);
      *reinterpret_cast<uint4*>(VsB + dr * 128 + ((c * 16) ^ ((dr & 7) << 4))) = v;
    }
    __syncthreads();   // staging visible

    // S = Q K^T for 4 kv-subtiles of 16
    f32x4 sacc[4];
#pragma unroll
    for (int kvs = 0; kvs < 4; ++kvs) {
      f32x4 a;
#pragma unroll
      for (int r = 0; r < 4; ++r) a[r] = 0.f;
      const int krow = kvs * 16 + lr;
      const char* kb = KsB + krow * 256;
      const int sw = (krow & 7) << 4;
#pragma unroll
      for (int dc = 0; dc < 4; ++dc) {
        bf16x8 kf = *reinterpret_cast<const bf16x8*>(kb + ((dc * 64 + g * 16) ^ sw));
        a = __builtin_amdgcn_mfma_f32_16x16x32_bf16(qf[dc], kf, a, 0, 0, 0);
      }
      sacc[kvs] = a;
    }

    // online softmax; P -> per-wave LDS (bf16)
#pragma unroll
    for (int r = 0; r < 4; ++r) {
      float mx = fmaxf(fmaxf(sacc[0][r], sacc[1][r]), fmaxf(sacc[2][r], sacc[3][r]));
#pragma unroll
      for (int off = 1; off < 16; off <<= 1) mx = fmaxf(mx, __shfl_xor(mx, off));
      float mnew = fmaxf(mrow[r], mx);
      float corr = exp2f((mrow[r] - mnew) * LOG2E);
      mrow[r] = mnew;
      float psum = 0.f;
#pragma unroll
      for (int kvs = 0; kvs < 4; ++kvs) {
        float p = exp2f((sacc[kvs][r] - mnew) * LOG2E);
        psum += p;
        Ps[w][(4 * g + r) * 72 + kvs * 16 + lr] = f2bf(p);
      }
#pragma unroll
      for (int off = 1; off < 16; off <<= 1) psum += __shfl_xor(psum, off);
      lrow[r] = lrow[r] * corr + psum;
#pragma unroll
      for (int dt = 0; dt < 8; ++dt) Oacc[dt][r] *= corr;
    }
    asm volatile("" ::: "memory");  // keep Ps writes before reads; DS is in-order per wave

    // O += P V   (A = P from Ps, B = V via V^T rows)
#pragma unroll
    for (int half = 0; half < 2; ++half) {
      bf16x8 pf = *reinterpret_cast<const bf16x8*>(&Ps[w][lr * 72 + half * 32 + g * 8]);
#pragma unroll
      for (int dt = 0; dt < 8; ++dt) {
        const int dr = dt * 16 + lr;
        bf16x8 vf = *reinterpret_cast<const bf16x8*>(
            VsB + dr * 128 + ((half * 64 + g * 16) ^ ((dr & 7) << 4)));
        Oacc[dt] = __builtin_amdgcn_mfma_f32_16x16x32_bf16(pf, vf, Oacc[dt], 0, 0, 0);
      }
    }
  }

  // epilogue: O / l
#pragma unroll
  for (int r = 0; r < 4; ++r) {
    float inv = 1.f / lrow[r];
    float* orow = out + ((size_t)(b * 2048 + q0 + 4 * g + r)) * 128;
#pragma unroll
    for (int dt = 0; dt < 8; ++dt) orow[dt * 16 + lr] = Oacc[dt][r] * inv;
  }
}

extern "C" void kernel_launch(void* const* d_in, const int* in_sizes, int n_in,
                              void* d_out, int out_size, void* d_ws, size_t ws_size,
                              hipStream_t stream) {
  const float* x  = (const float*)d_in[0];
  const float* Wq = (const float*)d_in[1];
  const float* bq = (const float*)d_in[2];
  const float* Wk = (const float*)d_in[3];
  const float* bk = (const float*)d_in[4];
  const float* Wv = (const float*)d_in[5];
  const float* bv = (const float*)d_in[6];
  float* out = (float*)d_out;

  u16* Qb  = (u16*)d_ws;                              // [B*N][128] bf16, 8 MB
  u16* Kb  = Qb + (size_t)16 * 2048 * 128;            // [B*N][128] bf16, 8 MB
  u16* VbT = Kb + (size_t)16 * 2048 * 128;            // [B][128][N] bf16, 8 MB

  proj_kernel<<<2048, 128, 0, stream>>>(x, Wq, bq, Wk, bk, Wv, bv, Qb, Kb, VbT);
  attn_kernel<<<512, 256, 0, stream>>>(Qb, Kb, VbT, out);
}

// Round 2
// 102.767 us; speedup vs baseline: 1.8157x; 1.8157x over previous
//
#include <hip/hip_runtime.h>

typedef unsigned short u16;
typedef unsigned int u32;
typedef __bf16 bf16x8 __attribute__((ext_vector_type(8)));
typedef float f32x4 __attribute__((ext_vector_type(4)));

#define QSCALE 0.18033688011112042f  // 0.125 * log2(e): softmax temp folded to base-2

__device__ __forceinline__ u16 bfbits(float f) {
  __bf16 h = (__bf16)f;            // RNE; compiler pairs into v_cvt_pk_bf16_f32
  return __builtin_bit_cast(u16, h);
}

// ---------------------------------------------------------------------------
// Projection: Qb = relu(x Wq + bq) * (0.125*log2e) (softmax scale folded),
// Kb = relu(x Wk + bk), VbT = relu(x Wv + bv) stored transposed [B][128][N].
// grid = 2048 blocks, 128 threads (thread = output column d).
// ---------------------------------------------------------------------------
__global__ __launch_bounds__(128) void proj_kernel(
    const float* __restrict__ x,
    const float* __restrict__ Wq, const float* __restrict__ bq,
    const float* __restrict__ Wk, const float* __restrict__ bk,
    const float* __restrict__ Wv, const float* __restrict__ bv,
    u16* __restrict__ Qb, u16* __restrict__ Kb, u16* __restrict__ VbT) {
  __shared__ float xs[16 * 64];
  const int t = threadIdx.x;                     // 0..127 == d
  const size_t rg0 = (size_t)blockIdx.x * 16;    // global row base (b*2048+n)

  const float4* xsrc = reinterpret_cast<const float4*>(x + rg0 * 64);
  float4* xdst = reinterpret_cast<float4*>(xs);
#pragma unroll
  for (int i = 0; i < 2; ++i) xdst[t + i * 128] = xsrc[t + i * 128];
  __syncthreads();

  float aq[16], ak[16], av[16];
#pragma unroll
  for (int r = 0; r < 16; ++r) { aq[r] = 0.f; ak[r] = 0.f; av[r] = 0.f; }
  for (int c = 0; c < 64; ++c) {
    float wq = Wq[c * 128 + t], wk = Wk[c * 128 + t], wv = Wv[c * 128 + t];
#pragma unroll
    for (int r = 0; r < 16; ++r) {
      float xv = xs[r * 64 + c];   // wave-uniform address -> LDS broadcast
      aq[r] = fmaf(xv, wq, aq[r]);
      ak[r] = fmaf(xv, wk, ak[r]);
      av[r] = fmaf(xv, wv, av[r]);
    }
  }
  const float biasq = bq[t], biask = bk[t], biasv = bv[t];
#pragma unroll
  for (int r = 0; r < 16; ++r) {
    Qb[(rg0 + r) * 128 + t] = bfbits(fmaxf(aq[r] + biasq, 0.f) * QSCALE);
    Kb[(rg0 + r) * 128 + t] = bfbits(fmaxf(ak[r] + biask, 0.f));
  }
  const int b = (int)(rg0 >> 11);
  const int n0 = (int)(rg0 & 2047);
  u32 pk[8];
#pragma unroll
  for (int i = 0; i < 8; ++i) {
    u16 lo = bfbits(fmaxf(av[2 * i] + biasv, 0.f));
    u16 hi = bfbits(fmaxf(av[2 * i + 1] + biasv, 0.f));
    pk[i] = (u32)lo | ((u32)hi << 16);
  }
  uint4* vdst = reinterpret_cast<uint4*>(VbT + ((size_t)(b * 128 + t)) * 2048 + n0);
  vdst[0] = make_uint4(pk[0], pk[1], pk[2], pk[3]);
  vdst[1] = make_uint4(pk[4], pk[5], pk[6], pk[7]);
}

// ---------------------------------------------------------------------------
// Flash attention. grid = 16 batches * 32 q-tiles = 512 blocks, 4 waves.
// Wave w owns q-rows [qt*64 + w*16, +16). KVBLK=64, double-buffered LDS,
// async stage (global loads issued before compute, ds_write after).
// QK^T computed SWAPPED: sacc = mfma(kf, qf) = S^T, so each lane owns one
// q-row (q=lane&15) -> in-register softmax reduce + 2 shfl steps.
// ---------------------------------------------------------------------------
__global__ __launch_bounds__(256) void attn_kernel(
    const u16* __restrict__ Qb, const u16* __restrict__ Kb,
    const u16* __restrict__ VbT, float* __restrict__ out) {
  __shared__ __align__(16) u16 Ks[2 * 64 * 128];   // [buf][kv][d], swizzled
  __shared__ __align__(16) u16 Vs[2 * 128 * 64];   // [buf][d][kv], swizzled
  __shared__ __align__(16) u16 Ps[4][16 * 72];     // per-wave P, row stride 72

  const int b = blockIdx.x >> 5;
  const int qt = blockIdx.x & 31;
  const int t = threadIdx.x, w = t >> 6, lane = t & 63;
  const int g = lane >> 4, lr = lane & 15;
  const int q0 = qt * 64 + w * 16;

  // Q fragments hoisted (scale folded in)
  bf16x8 qf[4];
  const u16* Qrow = Qb + ((size_t)(b * 2048 + q0 + lr)) * 128;
#pragma unroll
  for (int dc = 0; dc < 4; ++dc)
    qf[dc] = *reinterpret_cast<const bf16x8*>(Qrow + dc * 32 + g * 8);

  f32x4 Oacc[8];
#pragma unroll
  for (int dt = 0; dt < 8; ++dt)
#pragma unroll
    for (int r = 0; r < 4; ++r) Oacc[dt][r] = 0.f;
  float mloc = -INFINITY, lloc = 0.f;   // running max/sum for q-row (q0+lr)

  const u16* Kbase = Kb + (size_t)b * 2048 * 128;
  const u16* Vbase = VbT + (size_t)b * 128 * 2048;
  char* KsB = reinterpret_cast<char*>(Ks);
  char* VsB = reinterpret_cast<char*>(Vs);

  // staging geometry (fixed per thread): 8 x 16B chunks (4 K + 4 V)
  const u16* kgp[4]; const u16* vgp[4];
  int klds[4], vlds[4];
#pragma unroll
  for (int i = 0; i < 4; ++i) {
    int id = t + i * 256;
    int kr = id >> 4, kc = id & 15;          // K tile [64][128]
    kgp[i] = Kbase + (size_t)kr * 128 + kc * 8;
    klds[i] = kr * 256 + ((kc * 16) ^ ((kr & 7) << 4));
    int vr = id >> 3, vc = id & 7;           // V^T tile [128][64]
    vgp[i] = Vbase + (size_t)vr * 2048 + vc * 8;
    vlds[i] = vr * 128 + ((vc * 16) ^ ((vr & 7) << 4));
  }

  // prologue: stage tile 0 into buf0
  uint4 kpre[4], vpre[4];
#pragma unroll
  for (int i = 0; i < 4; ++i) {
    kpre[i] = *reinterpret_cast<const uint4*>(kgp[i]);
    vpre[i] = *reinterpret_cast<const uint4*>(vgp[i]);
  }
#pragma unroll
  for (int i = 0; i < 4; ++i) {
    *reinterpret_cast<uint4*>(KsB + klds[i]) = kpre[i];
    *reinterpret_cast<uint4*>(VsB + vlds[i]) = vpre[i];
  }
  __syncthreads();

  for (int kt = 0; kt < 32; ++kt) {
    const int cur = kt & 1;
    // async-stage: issue next tile's global loads NOW, consume after compute
    if (kt < 31) {
      const int nx = (kt + 1) * 64;
#pragma unroll
      for (int i = 0; i < 4; ++i) {
        kpre[i] = *reinterpret_cast<const uint4*>(kgp[i] + (size_t)nx * 128);
        vpre[i] = *reinterpret_cast<const uint4*>(vgp[i] + nx);
      }
    }
    const char* kb0 = KsB + cur * 16384;
    const char* vb0 = VsB + cur * 16384;

    // S^T = K Q^T : lane owns q-row (q0+lr); regs hold kv = kvs*16 + 4g + r
    f32x4 sacc[4];
#pragma unroll
    for (int kvs = 0; kvs < 4; ++kvs) {
      f32x4 a;
#pragma unroll
      for (int r = 0; r < 4; ++r) a[r] = 0.f;
      const int krw = kvs * 16 + lr;
      const char* kb = kb0 + krw * 256;
      const int sw = (krw & 7) << 4;
#pragma unroll
      for (int dc = 0; dc < 4; ++dc) {
        bf16x8 kf = *reinterpret_cast<const bf16x8*>(kb + ((dc * 64 + g * 16) ^ sw));
        a = __builtin_amdgcn_mfma_f32_16x16x32_bf16(kf, qf[dc], a, 0, 0, 0);
      }
      sacc[kvs] = a;
    }

    // online softmax, lane-local row
    float tmax = -INFINITY;
#pragma unroll
    for (int s = 0; s < 4; ++s)
#pragma unroll
      for (int r = 0; r < 4; ++r) tmax = fmaxf(tmax, sacc[s][r]);
    tmax = fmaxf(tmax, __shfl_xor(tmax, 16));
    tmax = fmaxf(tmax, __shfl_xor(tmax, 32));
    const float mnew = fmaxf(mloc, tmax);
    const float corr = exp2f(mloc - mnew);
    mloc = mnew;
    float p[4][4];
    float psum = 0.f;
#pragma unroll
    for (int s = 0; s < 4; ++s)
#pragma unroll
      for (int r = 0; r < 4; ++r) {
        p[s][r] = exp2f(sacc[s][r] - mnew);
        psum += p[s][r];
      }
    psum += __shfl_xor(psum, 16);
    psum += __shfl_xor(psum, 32);
    lloc = lloc * corr + psum;

    // redistribute corr to O-accumulator rows (q = 4g+r): 4 independent shfls
    float corrO[4];
#pragma unroll
    for (int r = 0; r < 4; ++r) corrO[r] = __shfl(corr, 4 * g + r);
#pragma unroll
    for (int dt = 0; dt < 8; ++dt)
#pragma unroll
      for (int r = 0; r < 4; ++r) Oacc[dt][r] *= corrO[r];

    // P -> per-wave LDS (paired bf16 stores)
    u32* prow = reinterpret_cast<u32*>(&Ps[w][lr * 72]);
#pragma unroll
    for (int s = 0; s < 4; ++s)
#pragma unroll
      for (int i = 0; i < 2; ++i) {
        u32 lo = bfbits(p[s][2 * i]);
        u32 hi = bfbits(p[s][2 * i + 1]);
        prow[s * 8 + 2 * g + i] = lo | (hi << 16);
      }
    asm volatile("" ::: "memory");  // order Ps writes before reads (same-wave DS)

    // O += P V
#pragma unroll
    for (int half = 0; half < 2; ++half) {
      bf16x8 pf = *reinterpret_cast<const bf16x8*>(&Ps[w][lr * 72 + half * 32 + g * 8]);
#pragma unroll
      for (int dt = 0; dt < 8; ++dt) {
        const int dr = dt * 16 + lr;
        bf16x8 vf = *reinterpret_cast<const bf16x8*>(
            vb0 + dr * 128 + ((half * 64 + g * 16) ^ ((dr & 7) << 4)));
        Oacc[dt] = __builtin_amdgcn_mfma_f32_16x16x32_bf16(pf, vf, Oacc[dt], 0, 0, 0);
      }
    }

    // write next tile into the other buffer (other waves already past their
    // reads of it: the barrier at end of iter kt-1 guarantees that)
    if (kt < 31) {
      char* kb1 = KsB + (cur ^ 1) * 16384;
      char* vb1 = VsB + (cur ^ 1) * 16384;
#pragma unroll
      for (int i = 0; i < 4; ++i) {
        *reinterpret_cast<uint4*>(kb1 + klds[i]) = kpre[i];
        *reinterpret_cast<uint4*>(vb1 + vlds[i]) = vpre[i];
      }
    }
    __syncthreads();
  }

  // epilogue: O / l  (l lives at lane q=lr; O rows are q=4g+r -> 4 shfls)
  const float invl = 1.f / lloc;
  float invO[4];
#pragma unroll
  for (int r = 0; r < 4; ++r) invO[r] = __shfl(invl, 4 * g + r);
#pragma unroll
  for (int r = 0; r < 4; ++r) {
    float* orow = out + ((size_t)(b * 2048 + q0 + 4 * g + r)) * 128;
#pragma unroll
    for (int dt = 0; dt < 8; ++dt) orow[dt * 16 + lr] = Oacc[dt][r] * invO[r];
  }
}

extern "C" void kernel_launch(void* const* d_in, const int* in_sizes, int n_in,
                              void* d_out, int out_size, void* d_ws, size_t ws_size,
                              hipStream_t stream) {
  const float* x  = (const float*)d_in[0];
  const float* Wq = (const float*)d_in[1];
  const float* bq = (const float*)d_in[2];
  const float* Wk = (const float*)d_in[3];
  const float* bk = (const float*)d_in[4];
  const float* Wv = (const float*)d_in[5];
  const float* bv = (const float*)d_in[6];
  float* out = (float*)d_out;

  u16* Qb  = (u16*)d_ws;                              // [B*N][128] bf16, 8 MB
  u16* Kb  = Qb + (size_t)16 * 2048 * 128;            // [B*N][128] bf16, 8 MB
  u16* VbT = Kb + (size_t)16 * 2048 * 128;            // [B][128][N] bf16, 8 MB

  proj_kernel<<<2048, 128, 0, stream>>>(x, Wq, bq, Wk, bk, Wv, bv, Qb, Kb, VbT);
  attn_kernel<<<512, 256, 0, stream>>>(Qb, Kb, VbT, out);
}